// Round 5
// baseline (637.448 us; speedup 1.0000x reference)
//
#include <hip/hip_runtime.h>

#define HD 256      // hidden
#define ED 160      // experts
#define TK 6        // top-k
#define ND 8        // devices
#define EPD 20      // experts per device
#define MD 3        // max devices per token
#define IN 768      // SwiGLU intermediate
#define TT 512      // tokens (B*S)
#define SL 128      // INTER slice per block
#define NSL 6       // IN / SL
#define CH 32       // token chunk per block
#define CAP 512     // per-expert token list capacity

typedef float f4 __attribute__((ext_vector_type(4)));

// ---------------- routing ----------------
__global__ __launch_bounds__(256) void k_route(
    const float* __restrict__ x, const float* __restrict__ Wr,
    float* __restrict__ P_sum, int* __restrict__ counts,
    int* __restrict__ tok_list, float* __restrict__ w_list)
{
  const int t   = blockIdx.x;
  const int tid = threadIdx.x;
  __shared__ float xs[HD];
  __shared__ float sc[ED];

  xs[tid] = x[(size_t)t * HD + tid];
  __syncthreads();

  if (tid < ED) {
    const float* wp = Wr + tid;
    float acc = 0.f;
    #pragma unroll 4
    for (int h = 0; h < HD; ++h) acc = fmaf(xs[h], wp[h * ED], acc);
    sc[tid] = acc;
  }
  __syncthreads();

  // softmax over 160 (serial in thread 0; trivial cost)
  if (tid == 0) {
    float m = sc[0];
    for (int e = 1; e < ED; ++e) m = fmaxf(m, sc[e]);
    float ss = 0.f;
    for (int e = 0; e < ED; ++e) { float v = __expf(sc[e] - m); sc[e] = v; ss += v; }
    float inv = 1.f / ss;
    for (int e = 0; e < ED; ++e) sc[e] *= inv;
  }
  __syncthreads();

  if (tid < ED) atomicAdd(&P_sum[tid], sc[tid]);
  __syncthreads();   // all P adds done before thread 0 clobbers sc below

  if (tid == 0) {
    // device scores (contiguous 20-expert blocks)
    float ds[ND];
    for (int d = 0; d < ND; ++d) {
      float s = 0.f;
      for (int j = 0; j < EPD; ++j) s += sc[d * EPD + j];
      ds[d] = s;
    }
    // top-3 devices (argmax scan; strict > matches lax.top_k tie order)
    unsigned dm = 0;
    for (int r = 0; r < MD; ++r) {
      int best = 0; float bv = -3e38f;
      for (int d = 0; d < ND; ++d)
        if (!((dm >> d) & 1) && ds[d] > bv) { bv = ds[d]; best = d; }
      dm |= 1u << best;
    }
    // top-6 experts among allowed devices
    int eidx[TK]; float ev[TK];
    for (int r = 0; r < TK; ++r) {
      int best = 0; float bv = -3e38f;
      for (int e = 0; e < ED; ++e) {
        if (!((dm >> (e / EPD)) & 1)) continue;
        float v = sc[e];
        if (v > bv) { bv = v; best = e; }
      }
      eidx[r] = best; ev[r] = bv; sc[best] = -3e38f;
    }
    // softmax over the 6 selected scores (ev[0] is the max)
    float mm = ev[0], ssum = 0.f, ww[TK];
    for (int r = 0; r < TK; ++r) { ww[r] = __expf(ev[r] - mm); ssum += ww[r]; }
    float inv2 = 1.f / ssum;
    for (int r = 0; r < TK; ++r) {
      float w = ww[r] * inv2;
      int e   = eidx[r];
      int pos = atomicAdd(&counts[e], 1);
      tok_list[e * CAP + pos] = t;
      w_list [e * CAP + pos] = w;
    }
  }
}

// ---------------- aux losses ----------------
__global__ void k_aux(const float* __restrict__ P_sum, const int* __restrict__ counts,
                      float* __restrict__ outs)
{
  __shared__ float P[ED];
  __shared__ float f[ED];
  __shared__ float cf[ED];
  const int tid = threadIdx.x;
  for (int e = tid; e < ED; e += blockDim.x) {
    P[e]  = P_sum[e] * (1.0f / TT);
    f[e]  = (float)counts[e] / (float)(TT * TK);
    cf[e] = (float)counts[e];
  }
  __syncthreads();
  if (tid == 0) {
    float eb = 0.f;
    for (int e = 0; e < ED; ++e) eb += f[e] * P[e];
    eb = fminf(eb * 0.003f, 10.0f);
    float db = 0.f, cb = 0.f;
    for (int d = 0; d < ND; ++d) {
      float df = 0.f, dP = 0.f, dc = 0.f;
      for (int j = 0; j < EPD; ++j) {
        df += f[d * EPD + j]; dP += P[d * EPD + j]; dc += cf[d * EPD + j];
      }
      db += (df * (1.0f / EPD)) * dP;          // dev_f (mean) * dev_P (sum)
      cb += (dc * (1.0f / (TT * MD))) * dP;    // f_comm * dev_P
    }
    db = fminf(db * 0.05f, 10.0f);
    cb = fminf(cb * 0.02f, 10.0f);
    outs[0] = eb; outs[1] = db; outs[2] = cb; outs[3] = eb + db + cb;
  }
}

// ---------------- expert FFN (routed + shared) ----------------
// One block = (expert e, INTER slice s of 128, token chunk c of <=32).
// Phase A: gu = x @ Wgu[:, slice] (per-thread 32-token accumulators, LDS x broadcast)
// Transition: act = silu(g)*u (g/u thread halves exchange via LDS)
// Phase B: partial y = act @ Wd[slice, :], weighted atomicAdd into out.
__global__ __launch_bounds__(256) void k_ffn(
    const float* __restrict__ x,
    const float* __restrict__ Wgu,
    const float* __restrict__ Wd,
    const int* __restrict__ counts,
    const int* __restrict__ tok_list,
    const float* __restrict__ w_list,
    float* __restrict__ out,
    const int shared_mode)
{
  __shared__ float sx[HD * CH];     // x^T chunk: sx[h*CH+i]; first SL*CH reused as actT
  __shared__ float sush[SL * 33];   // u exchange, padded stride 33 (conflict-free)
  __shared__ int   tl[CH];
  __shared__ float wl[CH];

  const int e = blockIdx.x, s = blockIdx.y, c = blockIdx.z;
  const int tid = threadIdx.x;
  const int n = shared_mode ? TT : counts[e];
  const int start = c * CH;
  if (start >= n) return;                 // uniform per block: barrier-safe
  const int nloc = min(CH, n - start);

  if (tid < nloc) {
    if (shared_mode) { tl[tid] = start + tid; wl[tid] = 1.0f; }
    else {
      tl[tid] = tok_list[e * CAP + start + tid];
      wl[tid] = w_list [e * CAP + start + tid];
    }
  }
  __syncthreads();
  for (int idx = tid; idx < nloc * HD; idx += 256) {
    const int i = idx >> 8, h = idx & (HD - 1);
    sx[h * CH + i] = x[(size_t)tl[i] * HD + h];   // coalesced global read
  }
  __syncthreads();

  const int  jj   = tid & (SL - 1);
  const bool is_u = tid >= SL;
  const float* wp = Wgu + (size_t)e * HD * (2 * IN) + (is_u ? IN : 0) + s * SL + jj;

  float acc[CH];
  #pragma unroll
  for (int i = 0; i < CH; ++i) acc[i] = 0.f;

  for (int h = 0; h < HD; h += 4) {
    const float w0 = wp[(size_t)(h + 0) * (2 * IN)];
    const float w1 = wp[(size_t)(h + 1) * (2 * IN)];
    const float w2 = wp[(size_t)(h + 2) * (2 * IN)];
    const float w3 = wp[(size_t)(h + 3) * (2 * IN)];
    #pragma unroll
    for (int g = 0; g < 8; ++g) {
      const f4 x0 = *(const f4*)(&sx[(h + 0) * CH + 4 * g]);   // broadcast reads:
      const f4 x1 = *(const f4*)(&sx[(h + 1) * CH + 4 * g]);   // same addr all lanes,
      const f4 x2 = *(const f4*)(&sx[(h + 2) * CH + 4 * g]);   // no bank conflicts
      const f4 x3 = *(const f4*)(&sx[(h + 3) * CH + 4 * g]);
      #pragma unroll
      for (int q = 0; q < 4; ++q) {
        float a = acc[4 * g + q];
        a = fmaf(x0[q], w0, a);
        a = fmaf(x1[q], w1, a);
        a = fmaf(x2[q], w2, a);
        a = fmaf(x3[q], w3, a);
        acc[4 * g + q] = a;
      }
    }
  }

  if (is_u) {
    #pragma unroll
    for (int i = 0; i < CH; ++i) sush[jj * 33 + i] = acc[i];
  }
  __syncthreads();                         // also: last use of sx as x^T is done
  float* actT = sx;                        // alias (SL*CH floats)
  if (!is_u) {
    #pragma unroll
    for (int i = 0; i < CH; ++i) {
      const float g  = acc[i];
      const float sg = g / (1.0f + __expf(-g));   // silu
      actT[jj * CH + i] = sg * sush[jj * 33 + i];
    }
  }
  __syncthreads();

  const float* wdp = Wd + (size_t)e * IN * HD + (size_t)s * SL * HD + tid;
  float acc2[CH];
  #pragma unroll
  for (int i = 0; i < CH; ++i) acc2[i] = 0.f;

  for (int k = 0; k < SL; k += 4) {
    const float w0 = wdp[(k + 0) * HD];
    const float w1 = wdp[(k + 1) * HD];
    const float w2 = wdp[(k + 2) * HD];
    const float w3 = wdp[(k + 3) * HD];
    #pragma unroll
    for (int g = 0; g < 8; ++g) {
      const f4 a0 = *(const f4*)(&actT[(k + 0) * CH + 4 * g]);
      const f4 a1 = *(const f4*)(&actT[(k + 1) * CH + 4 * g]);
      const f4 a2 = *(const f4*)(&actT[(k + 2) * CH + 4 * g]);
      const f4 a3 = *(const f4*)(&actT[(k + 3) * CH + 4 * g]);
      #pragma unroll
      for (int q = 0; q < 4; ++q) {
        float a = acc2[4 * g + q];
        a = fmaf(a0[q], w0, a);
        a = fmaf(a1[q], w1, a);
        a = fmaf(a2[q], w2, a);
        a = fmaf(a3[q], w3, a);
        acc2[4 * g + q] = a;
      }
    }
  }

  for (int i = 0; i < nloc; ++i) {
    atomicAdd(&out[(size_t)tl[i] * HD + tid], wl[i] * acc2[i]);
  }
}

// ---------------- launch ----------------
extern "C" void kernel_launch(void* const* d_in, const int* in_sizes, int n_in,
                              void* d_out, int out_size, void* d_ws, size_t ws_size,
                              hipStream_t stream)
{
  const float* x      = (const float*)d_in[0];
  const float* Wr     = (const float*)d_in[1];
  const float* Wgu_sh = (const float*)d_in[2];
  const float* Wd_sh  = (const float*)d_in[3];
  const float* Wgu    = (const float*)d_in[4];
  const float* Wd     = (const float*)d_in[5];
  float* out = (float*)d_out;

  float* P_sum    = (float*)d_ws;                      // 160 f
  int*   counts   = (int*)(P_sum + ED);                // 160 i
  int*   tok_list = (int*)(counts + ED);               // 160*512 i
  float* w_list   = (float*)(tok_list + ED * CAP);     // 160*512 f

  hipMemsetAsync(d_ws, 0, (size_t)(2 * ED) * sizeof(float), stream);      // P_sum + counts
  hipMemsetAsync(d_out, 0, (size_t)TT * HD * sizeof(float), stream);      // output accumulator

  k_route<<<TT, 256, 0, stream>>>(x, Wr, P_sum, counts, tok_list, w_list);
  k_aux<<<1, 256, 0, stream>>>(P_sum, counts, out + (size_t)TT * HD);
  k_ffn<<<dim3(ED, NSL, TT / CH), 256, 0, stream>>>(x, Wgu, Wd, counts, tok_list, w_list, out, 0);
  k_ffn<<<dim3(2,  NSL, TT / CH), 256, 0, stream>>>(x, Wgu_sh, Wd_sh, nullptr, nullptr, nullptr, out, 1);
}

// Round 7
// 595.228 us; speedup vs baseline: 1.0709x; 1.0709x over previous
//
#include <hip/hip_runtime.h>

#define HD 256      // hidden
#define ED 160      // routed experts
#define TK 6        // top-k
#define ND 8        // devices
#define EPD 20      // experts per device
#define MD 3        // max devices per token
#define IN 768      // SwiGLU intermediate
#define TT 512      // tokens (B*S)
#define SL 128      // INTER slice per block
#define NSL 6       // IN / SL
#define CH 32       // token chunk per block
#define CAP 512     // per-expert token list capacity

typedef float f4 __attribute__((ext_vector_type(4)));

// ---------------- routing ----------------
__global__ __launch_bounds__(256) void k_route(
    const float* __restrict__ x, const float* __restrict__ Wr,
    float* __restrict__ P_sum, int* __restrict__ counts,
    int* __restrict__ tok_list, float* __restrict__ w_list)
{
  const int t   = blockIdx.x;
  const int tid = threadIdx.x;
  __shared__ float xs[HD];
  __shared__ float sc[ED];

  xs[tid] = x[(size_t)t * HD + tid];
  __syncthreads();

  if (tid < ED) {
    const float* wp = Wr + tid;
    float acc = 0.f;
    #pragma unroll 4
    for (int h = 0; h < HD; ++h) acc = fmaf(xs[h], wp[h * ED], acc);
    sc[tid] = acc;
  }
  __syncthreads();

  if (tid == 0) {
    float m = sc[0];
    for (int e = 1; e < ED; ++e) m = fmaxf(m, sc[e]);
    float ss = 0.f;
    for (int e = 0; e < ED; ++e) { float v = __expf(sc[e] - m); sc[e] = v; ss += v; }
    float inv = 1.f / ss;
    for (int e = 0; e < ED; ++e) sc[e] *= inv;
  }
  __syncthreads();

  if (tid < ED) atomicAdd(&P_sum[tid], sc[tid]);
  __syncthreads();   // all P adds done before thread 0 clobbers sc below

  if (tid == 0) {
    float ds[ND];
    for (int d = 0; d < ND; ++d) {
      float s = 0.f;
      for (int j = 0; j < EPD; ++j) s += sc[d * EPD + j];
      ds[d] = s;
    }
    unsigned dm = 0;
    for (int r = 0; r < MD; ++r) {
      int best = 0; float bv = -3e38f;
      for (int d = 0; d < ND; ++d)
        if (!((dm >> d) & 1) && ds[d] > bv) { bv = ds[d]; best = d; }
      dm |= 1u << best;
    }
    int eidx[TK]; float ev[TK];
    for (int r = 0; r < TK; ++r) {
      int best = 0; float bv = -3e38f;
      for (int e = 0; e < ED; ++e) {
        if (!((dm >> (e / EPD)) & 1)) continue;
        float v = sc[e];
        if (v > bv) { bv = v; best = e; }
      }
      eidx[r] = best; ev[r] = bv; sc[best] = -3e38f;
    }
    float mm = ev[0], ssum = 0.f, ww[TK];
    for (int r = 0; r < TK; ++r) { ww[r] = __expf(ev[r] - mm); ssum += ww[r]; }
    float inv2 = 1.f / ssum;
    for (int r = 0; r < TK; ++r) {
      float w = ww[r] * inv2;
      int e   = eidx[r];
      int pos = atomicAdd(&counts[e], 1);
      tok_list[e * CAP + pos] = t;
      w_list [e * CAP + pos] = w;
    }
  }
}

// ---------------- aux losses ----------------
__global__ void k_aux(const float* __restrict__ P_sum, const int* __restrict__ counts,
                      float* __restrict__ outs)
{
  __shared__ float P[ED];
  __shared__ float f[ED];
  __shared__ float cf[ED];
  const int tid = threadIdx.x;
  for (int e = tid; e < ED; e += blockDim.x) {
    P[e]  = P_sum[e] * (1.0f / TT);
    f[e]  = (float)counts[e] / (float)(TT * TK);
    cf[e] = (float)counts[e];
  }
  __syncthreads();
  if (tid == 0) {
    float eb = 0.f;
    for (int e = 0; e < ED; ++e) eb += f[e] * P[e];
    eb = fminf(eb * 0.003f, 10.0f);
    float db = 0.f, cb = 0.f;
    for (int d = 0; d < ND; ++d) {
      float df = 0.f, dP = 0.f, dc = 0.f;
      for (int j = 0; j < EPD; ++j) {
        df += f[d * EPD + j]; dP += P[d * EPD + j]; dc += cf[d * EPD + j];
      }
      db += (df * (1.0f / EPD)) * dP;
      cb += (dc * (1.0f / (TT * MD))) * dP;
    }
    db = fminf(db * 0.05f, 10.0f);
    cb = fminf(cb * 0.02f, 10.0f);
    outs[0] = eb; outs[1] = db; outs[2] = cb; outs[3] = eb + db + cb;
  }
}

// ---------------- unified expert FFN (routed + shared fused) ----------------
// grid (ED+2, NSL, TT/CH). e<ED: routed expert; e>=ED: shared expert e-ED
// (all tokens, weight 1). One thread owns ONE inter-column (computes g AND u
// -> no exchange buffer), for 16 of the chunk's 32 tokens.
// LDS layouts are token-major so every write is lane-consecutive
// (conflict-free) and every compute read is a wave-broadcast f4.
__global__ __launch_bounds__(256) void k_ffn(
    const float* __restrict__ x,
    const float* __restrict__ Wgu,  const float* __restrict__ Wd,
    const float* __restrict__ Wgu_sh, const float* __restrict__ Wd_sh,
    const int* __restrict__ counts,
    const int* __restrict__ tok_list,
    const float* __restrict__ w_list,
    float* __restrict__ out)
{
  __shared__ float sx[CH * HD];     // sx[i*HD+h]; first CH*SL floats reused as actT[i*SL+k]
  __shared__ int   tl[CH];
  __shared__ float wl[CH];

  const int e = blockIdx.x, s = blockIdx.y, c = blockIdx.z;
  const int tid = threadIdx.x;
  const bool routed = (e < ED);
  const int n = routed ? counts[e] : TT;
  const int start = c * CH;
  if (start >= n) return;                 // uniform per block: barrier-safe
  const int nloc = min(CH, n - start);

  if (tid < nloc) {
    if (routed) {
      tl[tid] = tok_list[e * CAP + start + tid];
      wl[tid] = w_list [e * CAP + start + tid];
    } else { tl[tid] = start + tid; wl[tid] = 1.0f; }
  }
  __syncthreads();

  // stage x chunk as [i][h], f4-vectorized. Lane-consecutive global reads
  // (64 consecutive f4 within a token row) and lane-consecutive LDS writes.
  {
    const f4* xv = (const f4*)x;
    f4* sv = (f4*)sx;
    for (int idx = tid; idx < nloc * (HD / 4); idx += 256) {
      const int i = idx >> 6, hq = idx & 63;          // HD/4 = 64
      sv[i * 64 + hq] = xv[(size_t)tl[i] * 64 + hq];
    }
  }
  __syncthreads();

  const float* wgu_base = routed ? Wgu + (size_t)e * HD * (2 * IN)
                                 : Wgu_sh + (size_t)(e - ED) * HD * (2 * IN);
  const float* wd_base  = routed ? Wd + (size_t)e * IN * HD
                                 : Wd_sh + (size_t)(e - ED) * IN * HD;

  // ---- phase A: gu = x @ Wgu[:, s*SL + jj] for 16 tokens ----
  const int jj = tid & (SL - 1);          // inter column within slice
  const int ih = (tid >> 7) * 16;         // token sub-block (0 or 16)
  const float* wg = wgu_base + (size_t)(s * SL + jj);   // + h*2*IN per row
  float accg[16], accu[16];
  #pragma unroll
  for (int i = 0; i < 16; ++i) { accg[i] = 0.f; accu[i] = 0.f; }

  for (int h = 0; h < HD; h += 8) {
    float gw[8], uw[8];
    #pragma unroll
    for (int q = 0; q < 8; ++q) {
      gw[q] = wg[(size_t)(h + q) * (2 * IN)];
      uw[q] = wg[(size_t)(h + q) * (2 * IN) + IN];
    }
    #pragma unroll
    for (int i = 0; i < 16; ++i) {
      const f4 xa = *(const f4*)(&sx[(ih + i) * HD + h]);      // broadcast
      const f4 xb = *(const f4*)(&sx[(ih + i) * HD + h + 4]);  // broadcast
      float ag = accg[i], au = accu[i];
      ag = fmaf(xa[0], gw[0], ag); ag = fmaf(xa[1], gw[1], ag);
      ag = fmaf(xa[2], gw[2], ag); ag = fmaf(xa[3], gw[3], ag);
      ag = fmaf(xb[0], gw[4], ag); ag = fmaf(xb[1], gw[5], ag);
      ag = fmaf(xb[2], gw[6], ag); ag = fmaf(xb[3], gw[7], ag);
      au = fmaf(xa[0], uw[0], au); au = fmaf(xa[1], uw[1], au);
      au = fmaf(xa[2], uw[2], au); au = fmaf(xa[3], uw[3], au);
      au = fmaf(xb[0], uw[4], au); au = fmaf(xb[1], uw[5], au);
      au = fmaf(xb[2], uw[6], au); au = fmaf(xb[3], uw[7], au);
      accg[i] = ag; accu[i] = au;
    }
  }

  __syncthreads();                        // all sx reads done; safe to overwrite
  float* actT = sx;                       // alias: actT[i*SL + k], 16 KB
  #pragma unroll
  for (int i = 0; i < 16; ++i) {
    const float g  = accg[i];
    const float sg = g / (1.0f + __expf(-g));
    actT[(ih + i) * SL + jj] = sg * accu[i];   // lane-consecutive: conflict-free
  }
  __syncthreads();

  // ---- phase B: partial y = act @ Wd[s*SL:(s+1)*SL, :] for 32 tokens ----
  const float* wd = wd_base + (size_t)(s * SL) * HD + tid;   // + k*HD per row
  float acc2[32];
  #pragma unroll
  for (int i = 0; i < 32; ++i) acc2[i] = 0.f;

  for (int k = 0; k < SL; k += 8) {
    float w[8];
    #pragma unroll
    for (int q = 0; q < 8; ++q) w[q] = wd[(size_t)(k + q) * HD];
    #pragma unroll
    for (int i = 0; i < 32; ++i) {
      const f4 a = *(const f4*)(&actT[i * SL + k]);       // broadcast
      const f4 b = *(const f4*)(&actT[i * SL + k + 4]);   // broadcast
      float ac = acc2[i];
      ac = fmaf(a[0], w[0], ac); ac = fmaf(a[1], w[1], ac);
      ac = fmaf(a[2], w[2], ac); ac = fmaf(a[3], w[3], ac);
      ac = fmaf(b[0], w[4], ac); ac = fmaf(b[1], w[5], ac);
      ac = fmaf(b[2], w[6], ac); ac = fmaf(b[3], w[7], ac);
      acc2[i] = ac;
    }
  }

  #pragma unroll 4
  for (int i = 0; i < CH; ++i) {
    if (i < nloc)
      atomicAdd(&out[(size_t)tl[i] * HD + tid], wl[i] * acc2[i]);  // coalesced
  }
}

// ---------------- launch ----------------
extern "C" void kernel_launch(void* const* d_in, const int* in_sizes, int n_in,
                              void* d_out, int out_size, void* d_ws, size_t ws_size,
                              hipStream_t stream)
{
  const float* x      = (const float*)d_in[0];
  const float* Wr     = (const float*)d_in[1];
  const float* Wgu_sh = (const float*)d_in[2];
  const float* Wd_sh  = (const float*)d_in[3];
  const float* Wgu    = (const float*)d_in[4];
  const float* Wd     = (const float*)d_in[5];
  float* out = (float*)d_out;

  float* P_sum    = (float*)d_ws;                      // 160 f
  int*   counts   = (int*)(P_sum + ED);                // 160 i
  int*   tok_list = (int*)(counts + ED);               // 160*512 i
  float* w_list   = (float*)(tok_list + ED * CAP);     // 160*512 f

  hipMemsetAsync(d_ws, 0, (size_t)(2 * ED) * sizeof(float), stream);
  hipMemsetAsync(d_out, 0, (size_t)TT * HD * sizeof(float), stream);

  k_route<<<TT, 256, 0, stream>>>(x, Wr, P_sum, counts, tok_list, w_list);
  k_aux<<<1, 256, 0, stream>>>(P_sum, counts, out + (size_t)TT * HD);
  k_ffn<<<dim3(ED + 2, NSL, TT / CH), 256, 0, stream>>>(
      x, Wgu, Wd, Wgu_sh, Wd_sh, counts, tok_list, w_list, out);
}